// Round 1
// baseline (2497.979 us; speedup 1.0000x reference)
//
#include <hip/hip_runtime.h>
#include <hip/hip_bf16.h>
#include <cstdint>

// GraphQNet: N=20000 nodes, E=320000 edges, B=20 graphs (1000 nodes each),
// H=256 hidden, L=6 GINEConv layers.
// Design: fold ew2@lin_w[l] into per-layer W_l so the edge path is a single
// bf16 MFMA GEMM per layer (t[E,256] @ W_l[256,256]) with fused
// gather(h[src]) + relu + atomic-scatter(agg[dst]) epilogue.
// Residual stream h is fp32; all GEMM inputs bf16 (test threshold is bf16-floor).

#define NN 20000
#define EE 320000
#define BBG 20
#define PGN 1000
#define HH 256
#define LL 6

typedef short bf16x8 __attribute__((ext_vector_type(8)));
typedef float f32x4 __attribute__((ext_vector_type(4)));

__device__ __forceinline__ void async16(const void* g, void* l) {
  __builtin_amdgcn_global_load_lds(
      (const __attribute__((address_space(1))) unsigned int*)(uintptr_t)g,
      (__attribute__((address_space(3))) unsigned int*)(uintptr_t)l, 16, 0, 0);
}

__device__ __forceinline__ float siluf(float x) { return x / (1.f + __expf(-x)); }

enum { EPI_MSG = 0, EPI_SILU = 1, EPI_PLAIN = 2, EPI_TANH = 3 };

// C = A[M,256] @ W[256,256] (+bias), W given transposed: Wt[n][k].
// 128x128 tile, BK=32, 4 waves (2x2 of 64x64), mfma_f32_16x16x32_bf16.
template <int EPI>
__global__ void __launch_bounds__(256, 2) gemm256(
    const __hip_bfloat16* __restrict__ A, const __hip_bfloat16* __restrict__ Wt,
    const float* __restrict__ bias, int M, float* __restrict__ outf,
    __hip_bfloat16* __restrict__ outb, const float* __restrict__ hsrc,
    const int* __restrict__ esrc, const int* __restrict__ edst,
    float* __restrict__ agg) {
  __shared__ __align__(16) __hip_bfloat16 sA[128 * 32];
  __shared__ __align__(16) __hip_bfloat16 sB[128 * 32];
  __shared__ int sSrc[128], sDst[128];

  const int t = threadIdx.x;
  const int wave = t >> 6, lane = t & 63;
  const int row0 = blockIdx.x * 128;
  const int col0 = blockIdx.y * 128;

  if (EPI == EPI_MSG) {
    if (t < 128) { sSrc[t] = esrc[row0 + t]; sDst[t] = edst[row0 + t]; }
  }

  const int wrow = (wave >> 1) * 64;
  const int wcol = (wave & 1) * 64;
  const int fr = lane & 15, q = lane >> 4;

  f32x4 zero = {0.f, 0.f, 0.f, 0.f};
  f32x4 acc[4][4];
#pragma unroll
  for (int i = 0; i < 4; i++)
#pragma unroll
    for (int j = 0; j < 4; j++) acc[i][j] = zero;

  // staging: 8KB tile = 512 x 16B chunks; thread t handles chunks t and t+256.
  // chunk c: row=c>>2, in-row byte=(c&3)*16. LDS dst = wave-uniform base + lane*16.
  const int c1 = t, c2 = t + 256;
  int rA1 = row0 + (c1 >> 2); if (rA1 >= M) rA1 = M - 1;
  int rA2 = row0 + (c2 >> 2); if (rA2 >= M) rA2 = M - 1;
  const int rB1 = col0 + (c1 >> 2), rB2 = col0 + (c2 >> 2);

  for (int k0 = 0; k0 < 256; k0 += 32) {
    async16((const char*)(A + (size_t)rA1 * HH + k0) + (c1 & 3) * 16,
            (char*)sA + wave * 1024);
    async16((const char*)(A + (size_t)rA2 * HH + k0) + (c2 & 3) * 16,
            (char*)sA + 4096 + wave * 1024);
    async16((const char*)(Wt + (size_t)rB1 * HH + k0) + (c1 & 3) * 16,
            (char*)sB + wave * 1024);
    async16((const char*)(Wt + (size_t)rB2 * HH + k0) + (c2 & 3) * 16,
            (char*)sB + 4096 + wave * 1024);
    __syncthreads();
    bf16x8 af[4], bfr[4];
#pragma unroll
    for (int i = 0; i < 4; i++)
      af[i] = *(const bf16x8*)&sA[(wrow + i * 16 + fr) * 32 + q * 8];
#pragma unroll
    for (int j = 0; j < 4; j++)
      bfr[j] = *(const bf16x8*)&sB[(wcol + j * 16 + fr) * 32 + q * 8];
#pragma unroll
    for (int i = 0; i < 4; i++)
#pragma unroll
      for (int j = 0; j < 4; j++)
        acc[i][j] = __builtin_amdgcn_mfma_f32_16x16x32_bf16(af[i], bfr[j],
                                                            acc[i][j], 0, 0, 0);
    __syncthreads();
  }

  // C/D layout: col = lane&15, row = (lane>>4)*4 + reg  [m89-verified]
#pragma unroll
  for (int j = 0; j < 4; j++) {
    const int col = col0 + wcol + j * 16 + fr;
    const float bs = bias[col];
#pragma unroll
    for (int i = 0; i < 4; i++) {
      const int lr0 = wrow + i * 16 + q * 4;
#pragma unroll
      for (int r = 0; r < 4; r++) {
        const int lrow = lr0 + r;
        const int grow = row0 + lrow;
        float v = acc[i][j][r] + bs;
        if (EPI == EPI_MSG) {
          v += hsrc[(size_t)sSrc[lrow] * HH + col];
          v = v > 0.f ? v : 0.f;
          unsafeAtomicAdd(&agg[(size_t)sDst[lrow] * HH + col], v);
        } else if (EPI == EPI_SILU) {
          if (grow < M) outb[(size_t)grow * HH + col] = __float2bfloat16(siluf(v));
        } else if (EPI == EPI_PLAIN) {
          if (grow < M) outf[(size_t)grow * HH + col] = v;
        } else {
          if (grow < M) outb[(size_t)grow * HH + col] = __float2bfloat16(tanhf(v));
        }
      }
    }
  }
}

// W_l = ew2 @ lin_w[l] (store transposed bf16), b_l = eb2 @ lin_w[l] + lin_b[l]
__global__ void __launch_bounds__(256) fold_edge_w(
    const float* __restrict__ ew2, const float* __restrict__ lin_w,
    const float* __restrict__ eb2, const float* __restrict__ lin_b,
    __hip_bfloat16* __restrict__ Wlt, float* __restrict__ bl) {
  const int l = blockIdx.x >> 8, j = blockIdx.x & 255;
  const int c = threadIdx.x;
  __shared__ float row[256];
  row[c] = ew2[j * 256 + c];
  __syncthreads();
  const float* lw = lin_w + (size_t)l * 65536;
  float a = 0.f;
  for (int k = 0; k < 256; k++) a += row[k] * lw[k * 256 + c];
  Wlt[((size_t)l * 256 + c) * 256 + j] = __float2bfloat16(a);
  if (j == 0) {
    float s = lin_b[l * 256 + c];
    for (int k = 0; k < 256; k++) s += eb2[k] * lw[k * 256 + c];
    bl[l * 256 + c] = s;
  }
}

// transpose+cast fp32 [256,256] -> bf16 [256,256]^T for cw1(6), cw2(6), pa_w1(1)
__global__ void __launch_bounds__(256) tcast_all(
    const float* __restrict__ cw1, const float* __restrict__ cw2,
    const float* __restrict__ paw1, __hip_bfloat16* __restrict__ cw1t,
    __hip_bfloat16* __restrict__ cw2t, __hip_bfloat16* __restrict__ paw1t) {
  const int b = blockIdx.x;
  const float* s;
  __hip_bfloat16* d;
  if (b < 1536) { int l = b >> 8; s = cw1 + (size_t)l * 65536; d = cw1t + (size_t)l * 65536; }
  else if (b < 3072) { int l = (b - 1536) >> 8; s = cw2 + (size_t)l * 65536; d = cw2t + (size_t)l * 65536; }
  else { s = paw1; d = paw1t; }
  const int r = b & 255, c = threadIdx.x;
  d[(size_t)c * 256 + r] = __float2bfloat16(s[(size_t)r * 256 + c]);
}

// t = relu(ea @ ew1 + eb1) -> bf16, K=8
__global__ void __launch_bounds__(256) edge_hidden(
    const float* __restrict__ ea, const float* __restrict__ ew1,
    const float* __restrict__ eb1, __hip_bfloat16* __restrict__ tout) {
  __shared__ float w[8 * 256];
  __shared__ float b[256];
  __shared__ float sea[16 * 8];
  const int t = threadIdx.x;
  for (int i = t; i < 8 * 256; i += 256) w[i] = ew1[i];
  b[t] = eb1[t];
  const int e0 = blockIdx.x * 16;
  if (t < 128) sea[t] = ea[(size_t)e0 * 8 + t];
  __syncthreads();
  for (int e = 0; e < 16; e++) {
    float a = b[t];
#pragma unroll
    for (int j = 0; j < 8; j++) a += sea[e * 8 + j] * w[j * 256 + t];
    tout[(size_t)(e0 + e) * HH + t] = __float2bfloat16(a > 0.f ? a : 0.f);
  }
}

// h = silu([x, c_scalar] @ in_w + in_b), K=17
__global__ void __launch_bounds__(256) node_init(
    const float* __restrict__ x, const float* __restrict__ cc,
    const int* __restrict__ gid, const int* __restrict__ lid,
    const float* __restrict__ in_w, const float* __restrict__ in_b,
    float* __restrict__ h, __hip_bfloat16* __restrict__ hb) {
  __shared__ float w[17 * 256];
  __shared__ float b[256];
  __shared__ float sx[16 * 17];
  const int t = threadIdx.x;
  for (int i = t; i < 17 * 256; i += 256) w[i] = in_w[i];
  b[t] = in_b[t];
  const int n0 = blockIdx.x * 16;
  sx[(t >> 4) * 17 + (t & 15)] = x[(size_t)(n0 + (t >> 4)) * 16 + (t & 15)];
  if (t < 16) {
    int n = n0 + t;
    sx[t * 17 + 16] = cc[gid[n] * PGN + lid[n]];
  }
  __syncthreads();
  for (int e = 0; e < 16; e++) {
    float a = b[t];
#pragma unroll
    for (int j = 0; j < 17; j++) a += sx[e * 17 + j] * w[j * 256 + t];
    float s = siluf(a);
    size_t idx = (size_t)(n0 + e) * HH + t;
    h[idx] = s;
    hb[idx] = __float2bfloat16(s);
  }
}

// zb = bf16(h + agg); agg = 0 (ready for next layer's scatter)
__global__ void __launch_bounds__(256) z_prep(const float* __restrict__ h,
                                              float* __restrict__ agg,
                                              __hip_bfloat16* __restrict__ zb) {
  const size_t i = (size_t)blockIdx.x * 256 + threadIdx.x;
  float v = h[i] + agg[i];
  agg[i] = 0.f;
  zb[i] = __float2bfloat16(v);
}

// h += silu(LayerNorm(y)); also refresh bf16 copy. 1 wave per row, 4 rows/block.
__global__ void __launch_bounds__(256) ln_resid(
    const float* __restrict__ y, const float* __restrict__ g,
    const float* __restrict__ bb, float* __restrict__ h,
    __hip_bfloat16* __restrict__ hb) {
  const int t = threadIdx.x, wave = t >> 6, lane = t & 63;
  const size_t row = (size_t)blockIdx.x * 4 + wave;
  const float* yr = y + row * HH;
  float v[4];
  float s = 0.f;
#pragma unroll
  for (int i = 0; i < 4; i++) { v[i] = yr[lane + i * 64]; s += v[i]; }
#pragma unroll
  for (int o = 32; o; o >>= 1) s += __shfl_xor(s, o);
  const float mean = s * (1.f / 256.f);
  float var = 0.f;
#pragma unroll
  for (int i = 0; i < 4; i++) { float d = v[i] - mean; var += d * d; }
#pragma unroll
  for (int o = 32; o; o >>= 1) var += __shfl_xor(var, o);
  const float rs = rsqrtf(var * (1.f / 256.f) + 1e-5f);
#pragma unroll
  for (int i = 0; i < 4; i++) {
    const int c = lane + i * 64;
    float ln = (v[i] - mean) * rs * g[c] + bb[c];
    float si = siluf(ln);
    size_t idx = row * HH + c;
    float nh = h[idx] + si;
    h[idx] = nh;
    hb[idx] = __float2bfloat16(nh);
  }
}

// scores[n] = s1[n,:] . pa_w2 + pa_b2 ; per-block max -> pmax
__global__ void __launch_bounds__(256) score_k(
    const __hip_bfloat16* __restrict__ s1, const float* __restrict__ pw2,
    const float* __restrict__ pb2, float* __restrict__ scores,
    float* __restrict__ pmax) {
  __shared__ float w2[256];
  __shared__ float bm[4];
  const int t = threadIdx.x, wave = t >> 6, lane = t & 63;
  w2[t] = pw2[t];
  __syncthreads();
  const size_t row = (size_t)blockIdx.x * 4 + wave;
  float a = 0.f;
#pragma unroll
  for (int i = 0; i < 4; i++) {
    int c = lane + i * 64;
    a += __bfloat162float(s1[row * HH + c]) * w2[c];
  }
#pragma unroll
  for (int o = 32; o; o >>= 1) a += __shfl_xor(a, o);
  float sc = a + pb2[0];
  if (lane == 0) { scores[row] = sc; bm[wave] = sc; }
  __syncthreads();
  if (t == 0) pmax[blockIdx.x] = fmaxf(fmaxf(bm[0], bm[1]), fmaxf(bm[2], bm[3]));
}

__global__ void __launch_bounds__(256) gmax_k(const float* __restrict__ pmax,
                                              int n, float* __restrict__ gmax) {
  const int t = threadIdx.x;
  float m = -3.4e38f;
  for (int i = t; i < n; i += 256) m = fmaxf(m, pmax[i]);
#pragma unroll
  for (int o = 32; o; o >>= 1) m = fmaxf(m, __shfl_xor(m, o));
  __shared__ float wm[4];
  if ((t & 63) == 0) wm[t >> 6] = m;
  __syncthreads();
  if (t == 0) gmax[0] = fmaxf(fmaxf(wm[0], wm[1]), fmaxf(wm[2], wm[3]));
}

// en = exp(s - gmax); seg[g] += en ; seg[BBG] = total
__global__ void __launch_bounds__(256) esum_k(
    const float* __restrict__ scores, const int* __restrict__ gid,
    const float* __restrict__ gmax, float* __restrict__ en,
    float* __restrict__ seg) {
  __shared__ float ls[BBG + 1];
  const int t = threadIdx.x;
  if (t < BBG + 1) ls[t] = 0.f;
  __syncthreads();
  const int n = blockIdx.x * 256 + t;
  if (n < NN) {
    float e = __expf(scores[n] - gmax[0]);
    en[n] = e;
    atomicAdd(&ls[gid[n]], e);
    atomicAdd(&ls[BBG], e);
  }
  __syncthreads();
  if (t < BBG + 1) unsafeAtomicAdd(&seg[t], ls[t]);
}

// pooled[g,:] = sum_n en[n]*h[n,:] / (seg[g] + 1e-8*total)
__global__ void __launch_bounds__(256) pooled_k(
    const float* __restrict__ h, const float* __restrict__ en,
    const float* __restrict__ seg, float* __restrict__ pooled) {
  const int g = blockIdx.x >> 3, ch = blockIdx.x & 7;
  const int c = threadIdx.x;
  const int n0 = g * PGN + ch * 125;
  float a = 0.f;
  for (int i = 0; i < 125; i++) {
    int n = n0 + i;
    a += en[n] * h[(size_t)n * HH + c];
  }
  const float inv = 1.f / (seg[g] + 1e-8f * seg[BBG]);
  unsafeAtomicAdd(&pooled[g * HH + c], a * inv);
}

// q[b] = silu(pooled[b] @ hw1 + hb1) . hw2 + hb2
__global__ void __launch_bounds__(256) head_k(
    const float* __restrict__ pooled, const float* __restrict__ hw1,
    const float* __restrict__ hb1, const float* __restrict__ hw2,
    const float* __restrict__ hb2, float* __restrict__ qout) {
  const int b = blockIdx.x, c = threadIdx.x;
  __shared__ float p[256];
  __shared__ float wsum[4];
  p[c] = pooled[b * 256 + c];
  __syncthreads();
  float a = hb1[c];
  for (int k = 0; k < 256; k++) a += p[k] * hw1[k * 256 + c];
  float v = siluf(a) * hw2[c];
#pragma unroll
  for (int o = 32; o; o >>= 1) v += __shfl_xor(v, o);
  if ((c & 63) == 0) wsum[c >> 6] = v;
  __syncthreads();
  if (c == 0) qout[b] = wsum[0] + wsum[1] + wsum[2] + wsum[3] + hb2[0];
}

extern "C" void kernel_launch(void* const* d_in, const int* in_sizes, int n_in,
                              void* d_out, int out_size, void* d_ws, size_t ws_size,
                              hipStream_t stream) {
  const float* x = (const float*)d_in[0];
  const float* edge_attr = (const float*)d_in[1];
  const float* cc = (const float*)d_in[2];
  const int* edge_index = (const int*)d_in[3];
  const int* node_gid = (const int*)d_in[4];
  const int* node_lid = (const int*)d_in[5];
  const float* ew1 = (const float*)d_in[6];
  const float* eb1 = (const float*)d_in[7];
  const float* ew2 = (const float*)d_in[8];
  const float* eb2 = (const float*)d_in[9];
  const float* in_w = (const float*)d_in[10];
  const float* in_b = (const float*)d_in[11];
  const float* lin_w = (const float*)d_in[12];
  const float* lin_b = (const float*)d_in[13];
  const float* cw1 = (const float*)d_in[14];
  const float* cb1 = (const float*)d_in[15];
  const float* cw2 = (const float*)d_in[16];
  const float* cb2 = (const float*)d_in[17];
  const float* ln_g = (const float*)d_in[18];
  const float* ln_b = (const float*)d_in[19];
  const float* pa_w1 = (const float*)d_in[20];
  const float* pa_b1 = (const float*)d_in[21];
  const float* pa_w2 = (const float*)d_in[22];
  const float* pa_b2 = (const float*)d_in[23];
  const float* hw1 = (const float*)d_in[24];
  const float* hb1 = (const float*)d_in[25];
  const float* hw2 = (const float*)d_in[26];
  const float* hb2 = (const float*)d_in[27];
  float* qout = (float*)d_out;

  char* w = (char*)d_ws;
  auto alloc = [&](size_t bytes) {
    char* p = w;
    w += (bytes + 255) & ~(size_t)255;
    return p;
  };
  __hip_bfloat16* t_e = (__hip_bfloat16*)alloc((size_t)EE * HH * 2);  // 164 MB
  float* h = (float*)alloc((size_t)NN * HH * 4);
  __hip_bfloat16* hb = (__hip_bfloat16*)alloc((size_t)NN * HH * 2);
  float* agg = (float*)alloc((size_t)NN * HH * 4);
  __hip_bfloat16* zb = (__hip_bfloat16*)alloc((size_t)NN * HH * 2);
  __hip_bfloat16* t2 = (__hip_bfloat16*)alloc((size_t)NN * HH * 2);
  float* y = (float*)alloc((size_t)NN * HH * 4);
  __hip_bfloat16* Wlt = (__hip_bfloat16*)alloc((size_t)LL * HH * HH * 2);
  float* bl = (float*)alloc((size_t)LL * HH * 4);
  __hip_bfloat16* cw1t = (__hip_bfloat16*)alloc((size_t)LL * HH * HH * 2);
  __hip_bfloat16* cw2t = (__hip_bfloat16*)alloc((size_t)LL * HH * HH * 2);
  __hip_bfloat16* paw1t = (__hip_bfloat16*)alloc((size_t)HH * HH * 2);
  float* scores = (float*)alloc((size_t)NN * 4);
  float* pmax = (float*)alloc(5000 * 4);
  float* en = (float*)alloc((size_t)NN * 4);
  float* seg = (float*)alloc((BBG + 1) * 4);
  float* gmax = (float*)alloc(4);
  float* pooled = (float*)alloc((size_t)BBG * HH * 4);

  const int* esrc = edge_index;
  const int* edst = edge_index + EE;

  hipMemsetAsync(agg, 0, (size_t)NN * HH * 4, stream);
  hipMemsetAsync(seg, 0, (BBG + 1) * 4, stream);
  hipMemsetAsync(pooled, 0, (size_t)BBG * HH * 4, stream);

  fold_edge_w<<<LL * 256, 256, 0, stream>>>(ew2, lin_w, eb2, lin_b, Wlt, bl);
  tcast_all<<<3328, 256, 0, stream>>>(cw1, cw2, pa_w1, cw1t, cw2t, paw1t);
  edge_hidden<<<EE / 16, 256, 0, stream>>>(edge_attr, ew1, eb1, t_e);
  node_init<<<NN / 16, 256, 0, stream>>>(x, cc, node_gid, node_lid, in_w, in_b, h, hb);

  dim3 gE(EE / 128, 2), gN((NN + 127) / 128, 2);
  for (int l = 0; l < LL; l++) {
    gemm256<EPI_MSG><<<gE, 256, 0, stream>>>(
        t_e, Wlt + (size_t)l * HH * HH, bl + l * HH, EE, nullptr, nullptr, h,
        esrc, edst, agg);
    z_prep<<<NN * HH / 256, 256, 0, stream>>>(h, agg, zb);
    gemm256<EPI_SILU><<<gN, 256, 0, stream>>>(
        zb, cw1t + (size_t)l * HH * HH, cb1 + l * HH, NN, nullptr, t2, nullptr,
        nullptr, nullptr, nullptr);
    gemm256<EPI_PLAIN><<<gN, 256, 0, stream>>>(
        t2, cw2t + (size_t)l * HH * HH, cb2 + l * HH, NN, y, nullptr, nullptr,
        nullptr, nullptr, nullptr);
    ln_resid<<<NN / 4, 256, 0, stream>>>(y, ln_g + l * HH, ln_b + l * HH, h, hb);
  }

  gemm256<EPI_TANH><<<gN, 256, 0, stream>>>(hb, paw1t, pa_b1, NN, nullptr, t2,
                                            nullptr, nullptr, nullptr, nullptr);
  score_k<<<NN / 4, 256, 0, stream>>>(t2, pa_w2, pa_b2, scores, pmax);
  gmax_k<<<1, 256, 0, stream>>>(pmax, NN / 4, gmax);
  esum_k<<<(NN + 255) / 256, 256, 0, stream>>>(scores, node_gid, gmax, en, seg);
  pooled_k<<<BBG * 8, 256, 0, stream>>>(h, en, seg, pooled);
  head_k<<<BBG, 256, 0, stream>>>(pooled, hw1, hb1, hw2, hb2, qout);
}

// Round 3
// 1634.837 us; speedup vs baseline: 1.5280x; 1.5280x over previous
//
#include <hip/hip_runtime.h>
#include <hip/hip_bf16.h>
#include <cstdint>

// GraphQNet: N=20000 nodes, E=320000 edges, B=20 graphs (1000 each), H=256, L=6.
// R3: R2's CSR edge path, but t_e is never materialized (ws_size ~256MiB limit:
// R2's 386MiB workspace faulted). The edge GEMM computes A = relu(ea@ew1+eb1)
// on the fly from ea (10MB, L3-resident) via the sorted-order permutation, then
// U = A@W_l + b_l streams out; reduce_k does relu-free segment sums per node.

#define NN 20000
#define EE 320000
#define BBG 20
#define PGN 1000
#define HH 256
#define LL 6

typedef short bf16x8 __attribute__((ext_vector_type(8)));
typedef float f32x4 __attribute__((ext_vector_type(4)));

__device__ __forceinline__ void async16(const void* g, void* l) {
  __builtin_amdgcn_global_load_lds(
      (const __attribute__((address_space(1))) unsigned int*)(uintptr_t)g,
      (__attribute__((address_space(3))) unsigned int*)(uintptr_t)l, 16, 0, 0);
}

__device__ __forceinline__ float siluf(float x) { return x / (1.f + __expf(-x)); }

__device__ __forceinline__ unsigned short f2b(float x) {
  __hip_bfloat16 h = __float2bfloat16(x);
  return *(unsigned short*)&h;
}

enum { EPI_SILU = 1, EPI_PLAIN = 2, EPI_TANH = 3 };

// ---------------- node GEMM: C = A[M,256]@W^T (+bias) ----------------
// 128x128 tile, BK=32, 4 waves (2x2 of 64x64), mfma_f32_16x16x32_bf16.
// LDS 16B-chunk swizzle: slot s at row r holds global k-chunk s^((r>>1)&3).
template <int EPI>
__global__ void __launch_bounds__(256, 2) gemm256(
    const __hip_bfloat16* __restrict__ A, const __hip_bfloat16* __restrict__ Wt,
    const float* __restrict__ bias, int M, float* __restrict__ outf,
    __hip_bfloat16* __restrict__ outb) {
  __shared__ __align__(16) __hip_bfloat16 sA[128 * 32];
  __shared__ __align__(16) __hip_bfloat16 sB[128 * 32];

  const int t = threadIdx.x;
  const int wave = t >> 6, lane = t & 63;
  const int row0 = blockIdx.x * 128;
  const int col0 = blockIdx.y * 128;

  const int wrow = (wave >> 1) * 64;
  const int wcol = (wave & 1) * 64;
  const int fr = lane & 15, q = lane >> 4;

  f32x4 zero = {0.f, 0.f, 0.f, 0.f};
  f32x4 acc[4][4];
#pragma unroll
  for (int i = 0; i < 4; i++)
#pragma unroll
    for (int j = 0; j < 4; j++) acc[i][j] = zero;

  const int c1 = t, c2 = t + 256;
  const int lr1 = c1 >> 2, lr2 = c2 >> 2;
  const int q1 = (c1 & 3) ^ ((lr1 >> 1) & 3);
  const int q2 = (c2 & 3) ^ ((lr2 >> 1) & 3);
  int rA1 = row0 + lr1; if (rA1 >= M) rA1 = M - 1;
  int rA2 = row0 + lr2; if (rA2 >= M) rA2 = M - 1;
  const int rB1 = col0 + lr1, rB2 = col0 + lr2;

  for (int k0 = 0; k0 < 256; k0 += 32) {
    async16((const char*)(A + (size_t)rA1 * HH + k0) + q1 * 16,
            (char*)sA + wave * 1024);
    async16((const char*)(A + (size_t)rA2 * HH + k0) + q2 * 16,
            (char*)sA + 4096 + wave * 1024);
    async16((const char*)(Wt + (size_t)rB1 * HH + k0) + q1 * 16,
            (char*)sB + wave * 1024);
    async16((const char*)(Wt + (size_t)rB2 * HH + k0) + q2 * 16,
            (char*)sB + 4096 + wave * 1024);
    __syncthreads();
    bf16x8 af[4], bfr[4];
#pragma unroll
    for (int i = 0; i < 4; i++) {
      const int row = wrow + i * 16 + fr;
      af[i] = *(const bf16x8*)&sA[row * 32 + ((q ^ ((row >> 1) & 3))) * 8];
    }
#pragma unroll
    for (int j = 0; j < 4; j++) {
      const int row = wcol + j * 16 + fr;
      bfr[j] = *(const bf16x8*)&sB[row * 32 + ((q ^ ((row >> 1) & 3))) * 8];
    }
#pragma unroll
    for (int i = 0; i < 4; i++)
#pragma unroll
      for (int j = 0; j < 4; j++)
        acc[i][j] = __builtin_amdgcn_mfma_f32_16x16x32_bf16(af[i], bfr[j],
                                                            acc[i][j], 0, 0, 0);
    __syncthreads();
  }

  // C/D layout: col = lane&15, row = (lane>>4)*4 + reg  [m89-verified]
#pragma unroll
  for (int j = 0; j < 4; j++) {
    const int col = col0 + wcol + j * 16 + fr;
    const float bs = bias[col];
#pragma unroll
    for (int i = 0; i < 4; i++) {
      const int lr0 = wrow + i * 16 + q * 4;
#pragma unroll
      for (int r = 0; r < 4; r++) {
        const int grow = row0 + lr0 + r;
        float v = acc[i][j][r] + bs;
        if (grow < M) {
          if (EPI == EPI_SILU) {
            outb[(size_t)grow * HH + col] = __float2bfloat16(siluf(v));
          } else if (EPI == EPI_PLAIN) {
            outf[(size_t)grow * HH + col] = v;
          } else {
            outb[(size_t)grow * HH + col] = __float2bfloat16(tanhf(v));
          }
        }
      }
    }
  }
}

// ---------------- edge GEMM: U = relu(ea@ew1+eb1) @ W_l^T + b_l --------------
// A-tile computed on the fly: thread owns 4 rows x 4 cols of the 128x32 slice.
__global__ void __launch_bounds__(256, 2) gemm_edge(
    const float* __restrict__ ea, const int* __restrict__ eorig,
    const float* __restrict__ ew1f, const float* __restrict__ eb1f,
    const __hip_bfloat16* __restrict__ Wt, const float* __restrict__ bias,
    __hip_bfloat16* __restrict__ outb) {
  __shared__ __align__(16) __hip_bfloat16 sA[128 * 32];
  __shared__ __align__(16) __hip_bfloat16 sB[128 * 32];
  __shared__ __align__(16) float sew1[8 * 256];
  __shared__ __align__(16) float seb1[256];

  const int t = threadIdx.x;
  const int wave = t >> 6, lane = t & 63;
  const int row0 = blockIdx.x * 128;
  const int col0 = blockIdx.y * 128;

  // on-the-fly A assignment
  const int rr = (t >> 3) * 4;   // 4 rows of 128
  const int cc = (t & 7) * 4;    // 4 cols of the 32-wide k-slice
  float ar[4][8];
#pragma unroll
  for (int i = 0; i < 4; i++) {
    const int e = eorig[row0 + rr + i];
    const float4 a0 = *(const float4*)&ea[(size_t)e * 8];
    const float4 a1 = *(const float4*)&ea[(size_t)e * 8 + 4];
    ar[i][0] = a0.x; ar[i][1] = a0.y; ar[i][2] = a0.z; ar[i][3] = a0.w;
    ar[i][4] = a1.x; ar[i][5] = a1.y; ar[i][6] = a1.z; ar[i][7] = a1.w;
  }
  for (int i = t; i < 8 * 256; i += 256) sew1[i] = ew1f[i];
  seb1[t] = eb1f[t];

  const int wrow = (wave >> 1) * 64;
  const int wcol = (wave & 1) * 64;
  const int fr = lane & 15, q = lane >> 4;

  f32x4 zero = {0.f, 0.f, 0.f, 0.f};
  f32x4 acc[4][4];
#pragma unroll
  for (int i = 0; i < 4; i++)
#pragma unroll
    for (int j = 0; j < 4; j++) acc[i][j] = zero;

  // B staging (same as gemm256)
  const int c1 = t, c2 = t + 256;
  const int lr1 = c1 >> 2, lr2 = c2 >> 2;
  const int q1 = (c1 & 3) ^ ((lr1 >> 1) & 3);
  const int q2 = (c2 & 3) ^ ((lr2 >> 1) & 3);
  const int rB1 = col0 + lr1, rB2 = col0 + lr2;

  const int gch = cc >> 3;            // which 16B chunk (0..3)
  const int hby = (cc & 7) * 2;       // byte offset inside chunk (0 or 8)

  __syncthreads();  // sew1/seb1 ready

  for (int k0 = 0; k0 < 256; k0 += 32) {
    async16((const char*)(Wt + (size_t)rB1 * HH + k0) + q1 * 16,
            (char*)sB + wave * 1024);
    async16((const char*)(Wt + (size_t)rB2 * HH + k0) + q2 * 16,
            (char*)sB + 4096 + wave * 1024);

    // compute t-slice [128 x 32] = relu(ar @ ew1[:, k0:k0+32] + eb1)
    float tv[4][4];
    const float4 bb = *(const float4*)&seb1[k0 + cc];
#pragma unroll
    for (int i = 0; i < 4; i++) {
      tv[i][0] = bb.x; tv[i][1] = bb.y; tv[i][2] = bb.z; tv[i][3] = bb.w;
    }
#pragma unroll
    for (int j = 0; j < 8; j++) {
      const float4 ww = *(const float4*)&sew1[j * 256 + k0 + cc];
#pragma unroll
      for (int i = 0; i < 4; i++) {
        tv[i][0] += ar[i][j] * ww.x;
        tv[i][1] += ar[i][j] * ww.y;
        tv[i][2] += ar[i][j] * ww.z;
        tv[i][3] += ar[i][j] * ww.w;
      }
    }
#pragma unroll
    for (int i = 0; i < 4; i++) {
      const int r = rr + i;
      const int s = gch ^ ((r >> 1) & 3);
      ushort4 pk;
      pk.x = f2b(tv[i][0] > 0.f ? tv[i][0] : 0.f);
      pk.y = f2b(tv[i][1] > 0.f ? tv[i][1] : 0.f);
      pk.z = f2b(tv[i][2] > 0.f ? tv[i][2] : 0.f);
      pk.w = f2b(tv[i][3] > 0.f ? tv[i][3] : 0.f);
      *(ushort4*)((char*)sA + r * 64 + s * 16 + hby) = pk;
    }
    __syncthreads();
    bf16x8 af[4], bfr[4];
#pragma unroll
    for (int i = 0; i < 4; i++) {
      const int row = wrow + i * 16 + fr;
      af[i] = *(const bf16x8*)&sA[row * 32 + ((q ^ ((row >> 1) & 3))) * 8];
    }
#pragma unroll
    for (int j = 0; j < 4; j++) {
      const int row = wcol + j * 16 + fr;
      bfr[j] = *(const bf16x8*)&sB[row * 32 + ((q ^ ((row >> 1) & 3))) * 8];
    }
#pragma unroll
    for (int i = 0; i < 4; i++)
#pragma unroll
      for (int j = 0; j < 4; j++)
        acc[i][j] = __builtin_amdgcn_mfma_f32_16x16x32_bf16(af[i], bfr[j],
                                                            acc[i][j], 0, 0, 0);
    __syncthreads();
  }

#pragma unroll
  for (int j = 0; j < 4; j++) {
    const int col = col0 + wcol + j * 16 + fr;
    const float bs = bias[col];
#pragma unroll
    for (int i = 0; i < 4; i++) {
      const int lr0 = wrow + i * 16 + q * 4;
#pragma unroll
      for (int r = 0; r < 4; r++) {
        const int grow = row0 + lr0 + r;
        outb[(size_t)grow * HH + col] = __float2bfloat16(acc[i][j][r] + bs);
      }
    }
  }
}

// ---- CSR build (per-launch; edge_index is a fixed input) ----
__global__ void __launch_bounds__(256) hist_k(const int* __restrict__ edst,
                                              int* __restrict__ cnt) {
  const int e = blockIdx.x * 256 + threadIdx.x;
  if (e < EE) atomicAdd(&cnt[edst[e]], 1);
}

__global__ void __launch_bounds__(256) scan_k(const int* __restrict__ cnt,
                                              int* __restrict__ rowptr) {
  __shared__ int buf[256];
  __shared__ int carry;
  const int t = threadIdx.x;
  if (t == 0) carry = 0;
  __syncthreads();
  for (int base = 0; base < NN; base += 256) {
    const int idx = base + t;
    int v = (idx < NN) ? cnt[idx] : 0;
    buf[t] = v;
    __syncthreads();
    for (int o = 1; o < 256; o <<= 1) {
      int x = (t >= o) ? buf[t - o] : 0;
      __syncthreads();
      buf[t] += x;
      __syncthreads();
    }
    if (idx < NN) rowptr[idx] = carry + buf[t] - v;
    __syncthreads();
    if (t == 255) carry += buf[255];
    __syncthreads();
  }
  if (t == 0) rowptr[NN] = carry;
}

// pos = cursor[dst]++ ; eorig[pos]=e ; srcp[pos]=src
__global__ void __launch_bounds__(256) scatter_k(
    const int* __restrict__ esrc, const int* __restrict__ edst,
    int* __restrict__ cursor, int* __restrict__ eorig, int* __restrict__ srcp) {
  const int e = blockIdx.x * 256 + threadIdx.x;
  if (e < EE) {
    const int d = edst[e];
    const int pos = atomicAdd(&cursor[d], 1);
    eorig[pos] = e;
    srcp[pos] = esrc[e];
  }
}

// zb[n] = bf16( h[n] + sum_{i in [rowptr[n],rowptr[n+1])} relu(U[i]+h[srcp[i]]) )
__global__ void __launch_bounds__(256) reduce_k(
    const float* __restrict__ h, const __hip_bfloat16* __restrict__ U,
    const int* __restrict__ rowptr, const int* __restrict__ srcp,
    __hip_bfloat16* __restrict__ zb) {
  const int n = blockIdx.x, t = threadIdx.x;
  const int s = rowptr[n], e = rowptr[n + 1];
  float acc = h[(size_t)n * HH + t];
  int i = s;
  for (; i + 1 < e; i += 2) {
    const int s0 = srcp[i], s1 = srcp[i + 1];
    float u0 = __bfloat162float(U[(size_t)i * HH + t]);
    float u1 = __bfloat162float(U[(size_t)(i + 1) * HH + t]);
    float m0 = u0 + h[(size_t)s0 * HH + t];
    float m1 = u1 + h[(size_t)s1 * HH + t];
    acc += (m0 > 0.f ? m0 : 0.f) + (m1 > 0.f ? m1 : 0.f);
  }
  if (i < e) {
    const int s0 = srcp[i];
    float m0 = __bfloat162float(U[(size_t)i * HH + t]) + h[(size_t)s0 * HH + t];
    acc += m0 > 0.f ? m0 : 0.f;
  }
  zb[(size_t)n * HH + t] = __float2bfloat16(acc);
}

// W_l = ew2 @ lin_w[l] (store transposed bf16), b_l = eb2 @ lin_w[l] + lin_b[l]
__global__ void __launch_bounds__(256) fold_edge_w(
    const float* __restrict__ ew2, const float* __restrict__ lin_w,
    const float* __restrict__ eb2, const float* __restrict__ lin_b,
    __hip_bfloat16* __restrict__ Wlt, float* __restrict__ bl) {
  const int l = blockIdx.x >> 8, j = blockIdx.x & 255;
  const int c = threadIdx.x;
  __shared__ float row[256];
  row[c] = ew2[j * 256 + c];
  __syncthreads();
  const float* lw = lin_w + (size_t)l * 65536;
  float a = 0.f;
  for (int k = 0; k < 256; k++) a += row[k] * lw[k * 256 + c];
  Wlt[((size_t)l * 256 + c) * 256 + j] = __float2bfloat16(a);
  if (j == 0) {
    float s = lin_b[l * 256 + c];
    for (int k = 0; k < 256; k++) s += eb2[k] * lw[k * 256 + c];
    bl[l * 256 + c] = s;
  }
}

// transpose+cast fp32 [256,256] -> bf16^T for cw1(6), cw2(6), pa_w1(1)
__global__ void __launch_bounds__(256) tcast_all(
    const float* __restrict__ cw1, const float* __restrict__ cw2,
    const float* __restrict__ paw1, __hip_bfloat16* __restrict__ cw1t,
    __hip_bfloat16* __restrict__ cw2t, __hip_bfloat16* __restrict__ paw1t) {
  const int b = blockIdx.x;
  const float* s;
  __hip_bfloat16* d;
  if (b < 1536) { int l = b >> 8; s = cw1 + (size_t)l * 65536; d = cw1t + (size_t)l * 65536; }
  else if (b < 3072) { int l = (b - 1536) >> 8; s = cw2 + (size_t)l * 65536; d = cw2t + (size_t)l * 65536; }
  else { s = paw1; d = paw1t; }
  const int r = b & 255, c = threadIdx.x;
  d[(size_t)c * 256 + r] = __float2bfloat16(s[(size_t)r * 256 + c]);
}

// h = silu([x, c_scalar] @ in_w + in_b), K=17
__global__ void __launch_bounds__(256) node_init(
    const float* __restrict__ x, const float* __restrict__ cc,
    const int* __restrict__ gid, const int* __restrict__ lid,
    const float* __restrict__ in_w, const float* __restrict__ in_b,
    float* __restrict__ h) {
  __shared__ float w[17 * 256];
  __shared__ float b[256];
  __shared__ float sx[16 * 17];
  const int t = threadIdx.x;
  for (int i = t; i < 17 * 256; i += 256) w[i] = in_w[i];
  b[t] = in_b[t];
  const int n0 = blockIdx.x * 16;
  sx[(t >> 4) * 17 + (t & 15)] = x[(size_t)(n0 + (t >> 4)) * 16 + (t & 15)];
  if (t < 16) {
    int n = n0 + t;
    sx[t * 17 + 16] = cc[gid[n] * PGN + lid[n]];
  }
  __syncthreads();
  for (int e = 0; e < 16; e++) {
    float a = b[t];
#pragma unroll
    for (int j = 0; j < 17; j++) a += sx[e * 17 + j] * w[j * 256 + t];
    h[(size_t)(n0 + e) * HH + t] = siluf(a);
  }
}

// h += silu(LayerNorm(y)); optional bf16 copy. 1 wave/row, 4 rows/block.
__global__ void __launch_bounds__(256) ln_resid(
    const float* __restrict__ y, const float* __restrict__ g,
    const float* __restrict__ bb, float* __restrict__ h,
    __hip_bfloat16* __restrict__ hb) {
  const int t = threadIdx.x, wave = t >> 6, lane = t & 63;
  const size_t row = (size_t)blockIdx.x * 4 + wave;
  const float* yr = y + row * HH;
  float v[4];
  float s = 0.f;
#pragma unroll
  for (int i = 0; i < 4; i++) { v[i] = yr[lane + i * 64]; s += v[i]; }
#pragma unroll
  for (int o = 32; o; o >>= 1) s += __shfl_xor(s, o);
  const float mean = s * (1.f / 256.f);
  float var = 0.f;
#pragma unroll
  for (int i = 0; i < 4; i++) { float d = v[i] - mean; var += d * d; }
#pragma unroll
  for (int o = 32; o; o >>= 1) var += __shfl_xor(var, o);
  const float rs = rsqrtf(var * (1.f / 256.f) + 1e-5f);
#pragma unroll
  for (int i = 0; i < 4; i++) {
    const int c = lane + i * 64;
    float ln = (v[i] - mean) * rs * g[c] + bb[c];
    float si = siluf(ln);
    size_t idx = row * HH + c;
    float nh = h[idx] + si;
    h[idx] = nh;
    if (hb) hb[idx] = __float2bfloat16(nh);
  }
}

// scores[n] = s1[n,:] . pa_w2 + pa_b2 ; per-block max -> pmax
__global__ void __launch_bounds__(256) score_k(
    const __hip_bfloat16* __restrict__ s1, const float* __restrict__ pw2,
    const float* __restrict__ pb2, float* __restrict__ scores,
    float* __restrict__ pmax) {
  __shared__ float w2[256];
  __shared__ float bm[4];
  const int t = threadIdx.x, wave = t >> 6, lane = t & 63;
  w2[t] = pw2[t];
  __syncthreads();
  const size_t row = (size_t)blockIdx.x * 4 + wave;
  float a = 0.f;
#pragma unroll
  for (int i = 0; i < 4; i++) {
    int c = lane + i * 64;
    a += __bfloat162float(s1[row * HH + c]) * w2[c];
  }
#pragma unroll
  for (int o = 32; o; o >>= 1) a += __shfl_xor(a, o);
  float sc = a + pb2[0];
  if (lane == 0) { scores[row] = sc; bm[wave] = sc; }
  __syncthreads();
  if (t == 0) pmax[blockIdx.x] = fmaxf(fmaxf(bm[0], bm[1]), fmaxf(bm[2], bm[3]));
}

__global__ void __launch_bounds__(256) gmax_k(const float* __restrict__ pmax,
                                              int n, float* __restrict__ gmax) {
  const int t = threadIdx.x;
  float m = -3.4e38f;
  for (int i = t; i < n; i += 256) m = fmaxf(m, pmax[i]);
#pragma unroll
  for (int o = 32; o; o >>= 1) m = fmaxf(m, __shfl_xor(m, o));
  __shared__ float wm[4];
  if ((t & 63) == 0) wm[t >> 6] = m;
  __syncthreads();
  if (t == 0) gmax[0] = fmaxf(fmaxf(wm[0], wm[1]), fmaxf(wm[2], wm[3]));
}

// en = exp(s - gmax); seg[g] += en ; seg[BBG] = total
__global__ void __launch_bounds__(256) esum_k(
    const float* __restrict__ scores, const int* __restrict__ gid,
    const float* __restrict__ gmax, float* __restrict__ en,
    float* __restrict__ seg) {
  __shared__ float ls[BBG + 1];
  const int t = threadIdx.x;
  if (t < BBG + 1) ls[t] = 0.f;
  __syncthreads();
  const int n = blockIdx.x * 256 + t;
  if (n < NN) {
    float e = __expf(scores[n] - gmax[0]);
    en[n] = e;
    atomicAdd(&ls[gid[n]], e);
    atomicAdd(&ls[BBG], e);
  }
  __syncthreads();
  if (t < BBG + 1) unsafeAtomicAdd(&seg[t], ls[t]);
}

// pooled[g,:] = sum_n en[n]*h[n,:] / (seg[g] + 1e-8*total)
__global__ void __launch_bounds__(256) pooled_k(
    const float* __restrict__ h, const float* __restrict__ en,
    const float* __restrict__ seg, float* __restrict__ pooled) {
  const int g = blockIdx.x >> 3, ch = blockIdx.x & 7;
  const int c = threadIdx.x;
  const int n0 = g * PGN + ch * 125;
  float a = 0.f;
  for (int i = 0; i < 125; i++) {
    int n = n0 + i;
    a += en[n] * h[(size_t)n * HH + c];
  }
  const float inv = 1.f / (seg[g] + 1e-8f * seg[BBG]);
  unsafeAtomicAdd(&pooled[g * HH + c], a * inv);
}

// q[b] = silu(pooled[b] @ hw1 + hb1) . hw2 + hb2
__global__ void __launch_bounds__(256) head_k(
    const float* __restrict__ pooled, const float* __restrict__ hw1,
    const float* __restrict__ hb1, const float* __restrict__ hw2,
    const float* __restrict__ hb2, float* __restrict__ qout) {
  const int b = blockIdx.x, c = threadIdx.x;
  __shared__ float p[256];
  __shared__ float wsum[4];
  p[c] = pooled[b * 256 + c];
  __syncthreads();
  float a = hb1[c];
  for (int k = 0; k < 256; k++) a += p[k] * hw1[k * 256 + c];
  float v = siluf(a) * hw2[c];
#pragma unroll
  for (int o = 32; o; o >>= 1) v += __shfl_xor(v, o);
  if ((c & 63) == 0) wsum[c >> 6] = v;
  __syncthreads();
  if (c == 0) qout[b] = wsum[0] + wsum[1] + wsum[2] + wsum[3] + hb2[0];
}

extern "C" void kernel_launch(void* const* d_in, const int* in_sizes, int n_in,
                              void* d_out, int out_size, void* d_ws, size_t ws_size,
                              hipStream_t stream) {
  const float* x = (const float*)d_in[0];
  const float* edge_attr = (const float*)d_in[1];
  const float* cc = (const float*)d_in[2];
  const int* edge_index = (const int*)d_in[3];
  const int* node_gid = (const int*)d_in[4];
  const int* node_lid = (const int*)d_in[5];
  const float* ew1 = (const float*)d_in[6];
  const float* eb1 = (const float*)d_in[7];
  const float* ew2 = (const float*)d_in[8];
  const float* eb2 = (const float*)d_in[9];
  const float* in_w = (const float*)d_in[10];
  const float* in_b = (const float*)d_in[11];
  const float* lin_w = (const float*)d_in[12];
  const float* lin_b = (const float*)d_in[13];
  const float* cw1 = (const float*)d_in[14];
  const float* cb1 = (const float*)d_in[15];
  const float* cw2 = (const float*)d_in[16];
  const float* cb2 = (const float*)d_in[17];
  const float* ln_g = (const float*)d_in[18];
  const float* ln_b = (const float*)d_in[19];
  const float* pa_w1 = (const float*)d_in[20];
  const float* pa_b1 = (const float*)d_in[21];
  const float* pa_w2 = (const float*)d_in[22];
  const float* pa_b2 = (const float*)d_in[23];
  const float* hw1 = (const float*)d_in[24];
  const float* hb1 = (const float*)d_in[25];
  const float* hw2 = (const float*)d_in[26];
  const float* hb2 = (const float*)d_in[27];
  float* qout = (float*)d_out;

  char* w = (char*)d_ws;
  auto alloc = [&](size_t bytes) {
    char* p = w;
    w += (bytes + 255) & ~(size_t)255;
    return p;
  };
  // total ~241 MB (< 256 MiB ws)
  __hip_bfloat16* U = (__hip_bfloat16*)alloc((size_t)EE * HH * 2);  // 164 MB
  float* h = (float*)alloc((size_t)NN * HH * 4);
  __hip_bfloat16* hb = (__hip_bfloat16*)alloc((size_t)NN * HH * 2);
  __hip_bfloat16* zb = (__hip_bfloat16*)alloc((size_t)NN * HH * 2);
  __hip_bfloat16* t2 = (__hip_bfloat16*)alloc((size_t)NN * HH * 2);
  float* y = (float*)alloc((size_t)NN * HH * 4);
  __hip_bfloat16* Wlt = (__hip_bfloat16*)alloc((size_t)LL * HH * HH * 2);
  float* bl = (float*)alloc((size_t)LL * HH * 4);
  __hip_bfloat16* cw1t = (__hip_bfloat16*)alloc((size_t)LL * HH * HH * 2);
  __hip_bfloat16* cw2t = (__hip_bfloat16*)alloc((size_t)LL * HH * HH * 2);
  __hip_bfloat16* paw1t = (__hip_bfloat16*)alloc((size_t)HH * HH * 2);
  float* scores = (float*)alloc((size_t)NN * 4);
  float* pmax = (float*)alloc(5008 * 4);
  float* en = (float*)alloc((size_t)NN * 4);
  float* seg = (float*)alloc((BBG + 1) * 4);
  float* gmax = (float*)alloc(4);
  float* pooled = (float*)alloc((size_t)BBG * HH * 4);
  int* cnt = (int*)alloc((size_t)NN * 4);
  int* rowptr = (int*)alloc((size_t)(NN + 1) * 4);
  int* cursor = (int*)alloc((size_t)NN * 4);
  int* eorig = (int*)alloc((size_t)EE * 4);
  int* srcp = (int*)alloc((size_t)EE * 4);

  const int* esrc = edge_index;
  const int* edst = edge_index + EE;

  hipMemsetAsync(cnt, 0, (size_t)NN * 4, stream);
  hipMemsetAsync(seg, 0, (BBG + 1) * 4, stream);
  hipMemsetAsync(pooled, 0, (size_t)BBG * HH * 4, stream);

  // CSR build
  hist_k<<<(EE + 255) / 256, 256, 0, stream>>>(edst, cnt);
  scan_k<<<1, 256, 0, stream>>>(cnt, rowptr);
  hipMemcpyAsync(cursor, rowptr, (size_t)NN * 4, hipMemcpyDeviceToDevice, stream);
  scatter_k<<<(EE + 255) / 256, 256, 0, stream>>>(esrc, edst, cursor, eorig, srcp);

  fold_edge_w<<<LL * 256, 256, 0, stream>>>(ew2, lin_w, eb2, lin_b, Wlt, bl);
  tcast_all<<<3328, 256, 0, stream>>>(cw1, cw2, pa_w1, cw1t, cw2t, paw1t);
  node_init<<<NN / 16, 256, 0, stream>>>(x, cc, node_gid, node_lid, in_w, in_b, h);

  dim3 gE(EE / 128, 2), gN((NN + 127) / 128, 2);
  for (int l = 0; l < LL; l++) {
    gemm_edge<<<gE, 256, 0, stream>>>(edge_attr, eorig, ew1, eb1,
                                      Wlt + (size_t)l * HH * HH, bl + l * HH, U);
    reduce_k<<<NN, 256, 0, stream>>>(h, U, rowptr, srcp, zb);
    gemm256<EPI_SILU><<<gN, 256, 0, stream>>>(
        zb, cw1t + (size_t)l * HH * HH, cb1 + l * HH, NN, nullptr, t2);
    gemm256<EPI_PLAIN><<<gN, 256, 0, stream>>>(
        t2, cw2t + (size_t)l * HH * HH, cb2 + l * HH, NN, y, nullptr);
    ln_resid<<<NN / 4, 256, 0, stream>>>(y, ln_g + l * HH, ln_b + l * HH, h,
                                         (l == LL - 1) ? hb : (__hip_bfloat16*)nullptr);
  }

  gemm256<EPI_TANH><<<gN, 256, 0, stream>>>(hb, paw1t, pa_b1, NN, nullptr, t2);
  score_k<<<NN / 4, 256, 0, stream>>>(t2, pa_w2, pa_b2, scores, pmax);
  gmax_k<<<1, 256, 0, stream>>>(pmax, NN / 4, gmax);
  esum_k<<<(NN + 255) / 256, 256, 0, stream>>>(scores, node_gid, gmax, en, seg);
  pooled_k<<<BBG * 8, 256, 0, stream>>>(h, en, seg, pooled);
  head_k<<<BBG, 256, 0, stream>>>(pooled, hw1, hb1, hw2, hb2, qout);
}